// Round 1
// baseline (266.792 us; speedup 1.0000x reference)
//
#include <hip/hip_runtime.h>
#include <math.h>

#define NTOK 10000
#define BATCH 2
#define CDIM 128
#define NHEAD 4
#define NPNT 20
#define DHEAD 32
#define HWDIM 100

// ---------------------------------------------------------------------------
// Tiled row-wise projection: out[r][o] = dot(q[r], W[o]) + bias[o] (+resid)
// q row = src[r] (+ src2[r] if src2 != nullptr, used to fuse query+query_pos)
// MODE 0: out[r*O + o]
// MODE 1: value layout out[((b*NH + o/32)*NTOK + n)*32 + o%32]
// Block: 256 threads, 64 rows x 32-output tiles. LDS stride 132 (=128+4) so
// the 8 distinct row-addresses per wave hit distinct bank groups.
// ---------------------------------------------------------------------------
template <int MODE>
__global__ __launch_bounds__(256) void proj_kernel(
    const float* __restrict__ src, const float* __restrict__ src2,
    const float* __restrict__ W, const float* __restrict__ bias,
    float* __restrict__ out, const float* __restrict__ resid, int M, int O) {
  __shared__ float qs[64][132];
  __shared__ float wsm[32][132];
  const int t = threadIdx.x;
  const int r0 = blockIdx.x * 64;

  // stage 64 q rows (fused add of src2 if present)
  for (int i = t; i < 64 * 32; i += 256) {
    int r = i >> 5, c4 = (i & 31) << 2;
    float4 v = make_float4(0.f, 0.f, 0.f, 0.f);
    if (r0 + r < M) {
      v = *(const float4*)(src + (size_t)(r0 + r) * CDIM + c4);
      if (src2) {
        float4 u = *(const float4*)(src2 + (size_t)(r0 + r) * CDIM + c4);
        v.x += u.x; v.y += u.y; v.z += u.z; v.w += u.w;
      }
    }
    *(float4*)&qs[r][c4] = v;
  }

  const int orr = t & 7;   // output sub-group (lanes 0..7)
  const int rg = t >> 3;   // row group 0..31 -> rows rg and rg+32

  for (int ot = 0; ot < O; ot += 32) {
    __syncthreads();  // protect wsm from previous tile's readers (and qs 1st it)
    for (int i = t; i < 32 * 32; i += 256) {
      int o = i >> 5, c4 = (i & 31) << 2;
      float4 v = make_float4(0.f, 0.f, 0.f, 0.f);
      if (ot + o < O) v = *(const float4*)(W + (size_t)(ot + o) * CDIM + c4);
      *(float4*)&wsm[o][c4] = v;
    }
    __syncthreads();

    float accA[4] = {0.f, 0.f, 0.f, 0.f};
    float accB[4] = {0.f, 0.f, 0.f, 0.f};
    for (int c = 0; c < CDIM; c += 4) {
      float4 qa = *(const float4*)&qs[rg][c];
      float4 qb = *(const float4*)&qs[rg + 32][c];
#pragma unroll
      for (int j = 0; j < 4; ++j) {
        float4 w = *(const float4*)&wsm[orr + 8 * j][c];
        accA[j] += qa.x * w.x + qa.y * w.y + qa.z * w.z + qa.w * w.w;
        accB[j] += qb.x * w.x + qb.y * w.y + qb.z * w.z + qb.w * w.w;
      }
    }

#pragma unroll
    for (int j = 0; j < 4; ++j) {
      int o = ot + orr + 8 * j;
      if (o < O) {
        float bv = bias[o];
#pragma unroll
        for (int k = 0; k < 2; ++k) {
          int r = r0 + rg + 32 * k;
          float v = (k ? accB[j] : accA[j]) + bv;
          if (r < M) {
            if (MODE == 0) {
              if (resid) v += resid[(size_t)r * O + o];
              out[(size_t)r * O + o] = v;
            } else {
              int b = r / NTOK, n = r % NTOK;
              int h = o >> 5, d = o & 31;
              out[(((size_t)b * NHEAD + h) * NTOK + n) * DHEAD + d] = v;
            }
          }
        }
      }
    }
  }
}

// softmax over NP=20 per (b,n,h) group, in place
__global__ __launch_bounds__(256) void softmax_kernel(float* __restrict__ attn,
                                                      int G) {
  int g = blockIdx.x * 256 + threadIdx.x;
  if (g >= G) return;
  float* p = attn + (size_t)g * NPNT;
  float v[NPNT];
  float m = -1e30f;
#pragma unroll
  for (int i = 0; i < NPNT; ++i) {
    v[i] = p[i];
    m = fmaxf(m, v[i]);
  }
  float s = 0.f;
#pragma unroll
  for (int i = 0; i < NPNT; ++i) {
    v[i] = __expf(v[i] - m);
    s += v[i];
  }
  float inv = 1.f / s;
#pragma unroll
  for (int i = 0; i < NPNT; ++i) p[i] = v[i] * inv;
}

// Bilinear sampling + attention-weighted sum.
// thread t: d4 = t&7 (4 dims each), group g = t>>3 = (b*NTOK+n)*NH + h
// x = i + off_x, y = j + off_y exactly (the 0.5 terms cancel); idx = iy*HW+ix.
__global__ __launch_bounds__(256) void sample_kernel(
    const float* __restrict__ value, const float* __restrict__ off,
    const float* __restrict__ attn, float* __restrict__ out) {
  int t = blockIdx.x * 256 + threadIdx.x;  // 640000 threads
  int d4 = t & 7;
  int g = t >> 3;                 // (b*NTOK+n)*NH + h
  int h = g & 3;
  size_t r = (size_t)(g >> 2);    // b*NTOK + n
  int n = (int)(r % NTOK);
  int bh = (int)(r / NTOK) * NHEAD + h;
  const float* vbase = value + ((size_t)bh * NTOK) * DHEAD + d4 * 4;
  const float* obase = off + r * (NHEAD * NPNT * 2) + h * (NPNT * 2);
  const float* abase = attn + r * (NHEAD * NPNT) + h * NPNT;
  float fi = (float)(n / HWDIM);
  float fj = (float)(n % HWDIM);
  float ax = 0.f, ay = 0.f, az = 0.f, aw4 = 0.f;
  for (int p = 0; p < NPNT; ++p) {
    float x = fi + obase[2 * p];
    float y = fj + obase[2 * p + 1];
    float aw = abase[p];
    float x0f = floorf(x), y0f = floorf(y);
    int ix0 = (int)x0f, iy0 = (int)y0f;
    float wx1 = x - x0f, wy1 = y - y0f;
    float wx0 = 1.f - wx1, wy0 = 1.f - wy1;
#pragma unroll
    for (int cy = 0; cy < 2; ++cy) {
      int iy = iy0 + cy;
      if (iy < 0 || iy >= HWDIM) continue;
      float wy = cy ? wy1 : wy0;
#pragma unroll
      for (int cx = 0; cx < 2; ++cx) {
        int ix = ix0 + cx;
        if (ix < 0 || ix >= HWDIM) continue;
        float w = aw * wy * (cx ? wx1 : wx0);
        const float4 v = *(const float4*)(vbase + (size_t)(iy * HWDIM + ix) * DHEAD);
        ax += w * v.x; ay += w * v.y; az += w * v.z; aw4 += w * v.w;
      }
    }
  }
  float4 res = make_float4(ax, ay, az, aw4);
  *(float4*)(out + r * CDIM + h * DHEAD + d4 * 4) = res;
}

extern "C" void kernel_launch(void* const* d_in, const int* in_sizes, int n_in,
                              void* d_out, int out_size, void* d_ws,
                              size_t ws_size, hipStream_t stream) {
  const float* query = (const float*)d_in[0];
  const float* query_pos = (const float*)d_in[1];
  const float* W_val = (const float*)d_in[2];
  const float* b_val = (const float*)d_in[3];
  const float* W_off = (const float*)d_in[4];
  const float* b_off = (const float*)d_in[5];
  const float* W_attn = (const float*)d_in[6];
  const float* b_attn = (const float*)d_in[7];
  const float* W_out1 = (const float*)d_in[8];
  const float* b_out1 = (const float*)d_in[9];
  const float* W_out2 = (const float*)d_in[10];
  const float* b_out2 = (const float*)d_in[11];
  float* out = (float*)d_out;

  const int M = BATCH * NTOK;                 // 20000 rows
  const size_t QN = (size_t)M * CDIM;         // 2,560,000
  float* value = (float*)d_ws;                // (B,NH,N,DH)
  float* offb = value + QN;                   // (M,160)
  float* attnb = offb + (size_t)M * 160;      // (M,80)
  float* outat = attnb + (size_t)M * 80;      // (M,128)
  float* tmp = value;                         // reuse value region after sampling

  const int pb = (M + 63) / 64;  // 313 row-tiles

  // fused q = query + query_pos inside staging of each projection
  proj_kernel<1><<<pb, 256, 0, stream>>>(query, query_pos, W_val, b_val, value,
                                         nullptr, M, 128);
  proj_kernel<0><<<pb, 256, 0, stream>>>(query, query_pos, W_off, b_off, offb,
                                         nullptr, M, 160);
  proj_kernel<0><<<pb, 256, 0, stream>>>(query, query_pos, W_attn, b_attn,
                                         attnb, nullptr, M, 80);
  softmax_kernel<<<(M * NHEAD + 255) / 256, 256, 0, stream>>>(attnb, M * NHEAD);
  sample_kernel<<<(M * NHEAD * 8) / 256, 256, 0, stream>>>(value, offb, attnb,
                                                           outat);
  proj_kernel<0><<<pb, 256, 0, stream>>>(outat, nullptr, W_out1, b_out1, tmp,
                                         nullptr, M, 128);
  proj_kernel<0><<<pb, 256, 0, stream>>>(tmp, nullptr, W_out2, b_out2, out,
                                         query, M, 128);
}

// Round 2
// 156.980 us; speedup vs baseline: 1.6995x; 1.6995x over previous
//
#include <hip/hip_runtime.h>
#include <math.h>

#define NTOK 10000
#define BATCH 2
#define CDIM 128
#define NHEAD 4
#define NPNT 20
#define DHEAD 32
#define HWDIM 100
#define MROWS (BATCH * NTOK)

// ---------------------------------------------------------------------------
// Fold the two output projections: Wc = W2 @ W1, bc = b2 + W2 @ b1
// ---------------------------------------------------------------------------
__global__ __launch_bounds__(128) void fold_kernel(
    const float* __restrict__ W1, const float* __restrict__ b1,
    const float* __restrict__ W2, const float* __restrict__ b2,
    float* __restrict__ Wc, float* __restrict__ bc) {
  __shared__ float w2row[128];
  __shared__ float red[128];
  int o = blockIdx.x, c = threadIdx.x;
  w2row[c] = W2[o * 128 + c];
  __syncthreads();
  float acc = 0.f;
  for (int k = 0; k < 128; ++k) acc += w2row[k] * W1[k * 128 + c];
  Wc[o * 128 + c] = acc;
  red[c] = w2row[c] * b1[c];
  __syncthreads();
  for (int s = 64; s > 0; s >>= 1) {
    if (c < s) red[c] += red[c + s];
    __syncthreads();
  }
  if (c == 0) bc[o] = b2[o] + red[0];
}

#define DOT4(qq, ww) (qq.x * ww.x + qq.y * ww.y + qq.z * ww.z + qq.w * ww.w)

// ---------------------------------------------------------------------------
// Fused q-projections: q = query+query_pos staged once; three weight segments
// (value O=128, offsets O=160, attn logits O=80) with head-major outputs.
// 64 rows x 64 outs per tile, 256 threads, 4x4 register blocking.
// w tile XOR-swizzled (8 banks, 2-way = free); q padded stride 132.
// ---------------------------------------------------------------------------
__global__ __launch_bounds__(256) void fused_proj_kernel(
    const float* __restrict__ query, const float* __restrict__ qpos,
    const float* __restrict__ W_val, const float* __restrict__ b_val,
    const float* __restrict__ W_off, const float* __restrict__ b_off,
    const float* __restrict__ W_attn, const float* __restrict__ b_attn,
    float* __restrict__ value, float* __restrict__ offo,
    float* __restrict__ attno) {
  __shared__ float qs[64][132];
  __shared__ float wsm[64][128];
  const int t = threadIdx.x;
  const int r0 = blockIdx.x * 64;

  for (int i = t; i < 64 * 32; i += 256) {
    int r = i >> 5, c4 = (i & 31) << 2;
    float4 v = make_float4(0.f, 0.f, 0.f, 0.f);
    if (r0 + r < MROWS) {
      v = *(const float4*)(query + (size_t)(r0 + r) * CDIM + c4);
      float4 u = *(const float4*)(qpos + (size_t)(r0 + r) * CDIM + c4);
      v.x += u.x; v.y += u.y; v.z += u.z; v.w += u.w;
    }
    *(float4*)&qs[r][c4] = v;
  }

  const int ry4 = (t >> 4) << 2;  // row group: 4 rows
  const int ox = t & 15;          // out group: 4 outs
  const int ox4 = ox << 2;
  const int swz = (ox & 7) << 2;

#pragma unroll
  for (int seg = 0; seg < 3; ++seg) {
    const float* W = seg == 0 ? W_val : (seg == 1 ? W_off : W_attn);
    const float* bias = seg == 0 ? b_val : (seg == 1 ? b_off : b_attn);
    float* dst = seg == 0 ? value : (seg == 1 ? offo : attno);
    const int O = seg == 0 ? 128 : (seg == 1 ? 160 : 80);
    const int PER = seg == 0 ? 32 : (seg == 1 ? 40 : 20);

    for (int ot = 0; ot < O; ot += 64) {
      __syncthreads();
      for (int i = t; i < 64 * 32; i += 256) {
        int o = i >> 5, c4 = (i & 31) << 2;
        float4 v = make_float4(0.f, 0.f, 0.f, 0.f);
        if (ot + o < O) v = *(const float4*)(W + (size_t)(ot + o) * CDIM + c4);
        *(float4*)&wsm[o][c4 ^ (((o >> 2) & 7) << 2)] = v;
      }
      __syncthreads();

      float acc[4][4] = {{0.f}};
      for (int c = 0; c < CDIM; c += 4) {
        float4 q0 = *(const float4*)&qs[ry4 + 0][c];
        float4 q1 = *(const float4*)&qs[ry4 + 1][c];
        float4 q2 = *(const float4*)&qs[ry4 + 2][c];
        float4 q3 = *(const float4*)&qs[ry4 + 3][c];
        const int cs = c ^ swz;
        float4 w0 = *(const float4*)&wsm[ox4 + 0][cs];
        float4 w1 = *(const float4*)&wsm[ox4 + 1][cs];
        float4 w2 = *(const float4*)&wsm[ox4 + 2][cs];
        float4 w3 = *(const float4*)&wsm[ox4 + 3][cs];
        acc[0][0] += DOT4(q0, w0); acc[0][1] += DOT4(q0, w1);
        acc[0][2] += DOT4(q0, w2); acc[0][3] += DOT4(q0, w3);
        acc[1][0] += DOT4(q1, w0); acc[1][1] += DOT4(q1, w1);
        acc[1][2] += DOT4(q1, w2); acc[1][3] += DOT4(q1, w3);
        acc[2][0] += DOT4(q2, w0); acc[2][1] += DOT4(q2, w1);
        acc[2][2] += DOT4(q2, w2); acc[2][3] += DOT4(q2, w3);
        acc[3][0] += DOT4(q3, w0); acc[3][1] += DOT4(q3, w1);
        acc[3][2] += DOT4(q3, w2); acc[3][3] += DOT4(q3, w3);
      }

#pragma unroll
      for (int rr = 0; rr < 4; ++rr) {
        int r = r0 + ry4 + rr;
        if (r >= MROWS) continue;
        int b = r >= NTOK ? 1 : 0;
        int n = r - b * NTOK;
#pragma unroll
        for (int wr = 0; wr < 4; ++wr) {
          int o = ot + ox4 + wr;
          if (o >= O) continue;
          float v = acc[rr][wr] + bias[o];
          int h, rem;
          if (seg == 0) { h = o >> 5; rem = o & 31; }
          else if (seg == 1) { h = o / 40; rem = o - h * 40; }
          else { h = o / 20; rem = o - h * 20; }
          dst[(((size_t)b * NHEAD + h) * NTOK + n) * PER + rem] = v;
        }
      }
    }
  }
}

// ---------------------------------------------------------------------------
// Final output projection with folded weights + residual, row-major.
// ---------------------------------------------------------------------------
__global__ __launch_bounds__(256) void out_proj_kernel(
    const float* __restrict__ src, const float* __restrict__ Wc,
    const float* __restrict__ bc, const float* __restrict__ resid,
    float* __restrict__ out) {
  __shared__ float qs[64][132];
  __shared__ float wsm[64][128];
  const int t = threadIdx.x;
  const int r0 = blockIdx.x * 64;

  for (int i = t; i < 64 * 32; i += 256) {
    int r = i >> 5, c4 = (i & 31) << 2;
    float4 v = make_float4(0.f, 0.f, 0.f, 0.f);
    if (r0 + r < MROWS)
      v = *(const float4*)(src + (size_t)(r0 + r) * CDIM + c4);
    *(float4*)&qs[r][c4] = v;
  }

  const int ry4 = (t >> 4) << 2;
  const int ox = t & 15;
  const int ox4 = ox << 2;
  const int swz = (ox & 7) << 2;

  for (int ot = 0; ot < 128; ot += 64) {
    __syncthreads();
    for (int i = t; i < 64 * 32; i += 256) {
      int o = i >> 5, c4 = (i & 31) << 2;
      float4 v = *(const float4*)(Wc + (size_t)(ot + o) * CDIM + c4);
      *(float4*)&wsm[o][c4 ^ (((o >> 2) & 7) << 2)] = v;
    }
    __syncthreads();

    float acc[4][4] = {{0.f}};
    for (int c = 0; c < CDIM; c += 4) {
      float4 q0 = *(const float4*)&qs[ry4 + 0][c];
      float4 q1 = *(const float4*)&qs[ry4 + 1][c];
      float4 q2 = *(const float4*)&qs[ry4 + 2][c];
      float4 q3 = *(const float4*)&qs[ry4 + 3][c];
      const int cs = c ^ swz;
      float4 w0 = *(const float4*)&wsm[ox4 + 0][cs];
      float4 w1 = *(const float4*)&wsm[ox4 + 1][cs];
      float4 w2 = *(const float4*)&wsm[ox4 + 2][cs];
      float4 w3 = *(const float4*)&wsm[ox4 + 3][cs];
      acc[0][0] += DOT4(q0, w0); acc[0][1] += DOT4(q0, w1);
      acc[0][2] += DOT4(q0, w2); acc[0][3] += DOT4(q0, w3);
      acc[1][0] += DOT4(q1, w0); acc[1][1] += DOT4(q1, w1);
      acc[1][2] += DOT4(q1, w2); acc[1][3] += DOT4(q1, w3);
      acc[2][0] += DOT4(q2, w0); acc[2][1] += DOT4(q2, w1);
      acc[2][2] += DOT4(q2, w2); acc[2][3] += DOT4(q2, w3);
      acc[3][0] += DOT4(q3, w0); acc[3][1] += DOT4(q3, w1);
      acc[3][2] += DOT4(q3, w2); acc[3][3] += DOT4(q3, w3);
    }

#pragma unroll
    for (int rr = 0; rr < 4; ++rr) {
      int r = r0 + ry4 + rr;
      if (r >= MROWS) continue;
#pragma unroll
      for (int wr = 0; wr < 4; ++wr) {
        int o = ot + ox4 + wr;
        out[(size_t)r * CDIM + o] =
            acc[rr][wr] + bc[o] + resid[(size_t)r * CDIM + o];
      }
    }
  }
}

// ---------------------------------------------------------------------------
// Bilinear sampling + fused softmax. One (b,h) slice per block, slices pinned
// round-robin to XCDs via blockIdx.x & 7 (value slice = 1.28 MB < 4 MB L2).
// 8 threads per token, 4 dims each; head-major off/attn reads are contiguous.
// ---------------------------------------------------------------------------
__global__ __launch_bounds__(256) void sample_kernel(
    const float* __restrict__ value, const float* __restrict__ off,
    const float* __restrict__ attn, float* __restrict__ out) {
  const int s = blockIdx.x & 7;        // slice = b*NH + h
  const int blk = blockIdx.x >> 3;
  const int idx = blk * 256 + threadIdx.x;
  const int n = idx >> 3;
  if (n >= NTOK) return;
  const int d4 = idx & 7;
  const int b = s >> 2, h = s & 3;

  const float* vbase = value + (size_t)s * NTOK * DHEAD + d4 * 4;
  const float* obase = off + ((size_t)s * NTOK + n) * (NPNT * 2);
  const float* abase = attn + ((size_t)s * NTOK + n) * NPNT;

  // softmax over the 20 logits (redundant across the 8 lanes of this token)
  float v[NPNT];
  float m = -1e30f;
#pragma unroll
  for (int i = 0; i < NPNT; ++i) {
    v[i] = abase[i];
    m = fmaxf(m, v[i]);
  }
  float ssum = 0.f;
#pragma unroll
  for (int i = 0; i < NPNT; ++i) {
    v[i] = __expf(v[i] - m);
    ssum += v[i];
  }
  const float inv = 1.f / ssum;

  const float fi = (float)(n / HWDIM);
  const float fj = (float)(n % HWDIM);
  float ax = 0.f, ay = 0.f, az = 0.f, aw4 = 0.f;
  for (int p = 0; p < NPNT; ++p) {
    float x = fi + obase[2 * p];
    float y = fj + obase[2 * p + 1];
    float aw = v[p] * inv;
    float x0f = floorf(x), y0f = floorf(y);
    int ix0 = (int)x0f, iy0 = (int)y0f;
    float wx1 = x - x0f, wy1 = y - y0f;
    float wx0 = 1.f - wx1, wy0 = 1.f - wy1;
#pragma unroll
    for (int cy = 0; cy < 2; ++cy) {
      int iy = iy0 + cy;
      if (iy < 0 || iy >= HWDIM) continue;
      float wy = cy ? wy1 : wy0;
#pragma unroll
      for (int cx = 0; cx < 2; ++cx) {
        int ix = ix0 + cx;
        if (ix < 0 || ix >= HWDIM) continue;
        float w = aw * wy * (cx ? wx1 : wx0);
        const float4 g =
            *(const float4*)(vbase + (size_t)(iy * HWDIM + ix) * DHEAD);
        ax += w * g.x; ay += w * g.y; az += w * g.z; aw4 += w * g.w;
      }
    }
  }
  *(float4*)(out + ((size_t)b * NTOK + n) * CDIM + h * DHEAD + d4 * 4) =
      make_float4(ax, ay, az, aw4);
}

extern "C" void kernel_launch(void* const* d_in, const int* in_sizes, int n_in,
                              void* d_out, int out_size, void* d_ws,
                              size_t ws_size, hipStream_t stream) {
  const float* query = (const float*)d_in[0];
  const float* query_pos = (const float*)d_in[1];
  const float* W_val = (const float*)d_in[2];
  const float* b_val = (const float*)d_in[3];
  const float* W_off = (const float*)d_in[4];
  const float* b_off = (const float*)d_in[5];
  const float* W_attn = (const float*)d_in[6];
  const float* b_attn = (const float*)d_in[7];
  const float* W_out1 = (const float*)d_in[8];
  const float* b_out1 = (const float*)d_in[9];
  const float* W_out2 = (const float*)d_in[10];
  const float* b_out2 = (const float*)d_in[11];
  float* out = (float*)d_out;

  float* value = (float*)d_ws;                  // (B*NH, N, 32)
  float* offb = value + (size_t)MROWS * CDIM;   // (B*NH, N, 40)
  float* attnb = offb + (size_t)MROWS * 160;    // (B*NH, N, 20) logits
  float* outat = attnb + (size_t)MROWS * 80;    // (B, N, C)
  float* Wc = outat + (size_t)MROWS * CDIM;     // (128,128)
  float* bc = Wc + 128 * 128;                   // (128)

  const int pb = (MROWS + 63) / 64;  // 313

  fold_kernel<<<128, 128, 0, stream>>>(W_out1, b_out1, W_out2, b_out2, Wc, bc);
  fused_proj_kernel<<<pb, 256, 0, stream>>>(query, query_pos, W_val, b_val,
                                            W_off, b_off, W_attn, b_attn,
                                            value, offb, attnb);
  sample_kernel<<<313 * 8, 256, 0, stream>>>(value, offb, attnb, outat);
  out_proj_kernel<<<pb, 256, 0, stream>>>(outat, Wc, bc, query, out);
}

// Round 3
// 96.019 us; speedup vs baseline: 2.7785x; 1.6349x over previous
//
#include <hip/hip_runtime.h>
#include <hip/hip_bf16.h>
#include <math.h>

#define NTOK 10000
#define BATCH 2
#define CDIM 128
#define NHEAD 4
#define NPNT 20
#define DHEAD 32
#define HWDIM 100
#define MROWS (BATCH * NTOK)
#define OCAT 368   // 128 value + 160 off + 80 attn
#define OPAD 384   // padded to 64-multiple

typedef __attribute__((ext_vector_type(8))) short short8v;
typedef __attribute__((ext_vector_type(4))) float f32x4;

// ---------------------------------------------------------------------------
// Fold the two output projections: Wc = W2 @ W1, bc = b2 + W2 @ b1 (fp32)
// ---------------------------------------------------------------------------
__global__ __launch_bounds__(128) void fold_kernel(
    const float* __restrict__ W1, const float* __restrict__ b1,
    const float* __restrict__ W2, const float* __restrict__ b2,
    float* __restrict__ Wc, float* __restrict__ bc) {
  __shared__ float w2row[128];
  __shared__ float red[128];
  int o = blockIdx.x, c = threadIdx.x;
  w2row[c] = W2[o * 128 + c];
  __syncthreads();
  float acc = 0.f;
  for (int k = 0; k < 128; ++k) acc += w2row[k] * W1[k * 128 + c];
  Wc[o * 128 + c] = acc;
  red[c] = w2row[c] * b1[c];
  __syncthreads();
  for (int s = 64; s > 0; s >>= 1) {
    if (c < s) red[c] += red[c + s];
    __syncthreads();
  }
  if (c == 0) bc[o] = b2[o] + red[0];
}

// ---------------------------------------------------------------------------
// Convert weights to bf16: Wcat[384][128] = {W_val,W_off,W_attn,pad},
// bcat[384] = {b_val,b_off,b_attn,0}; Wc(fp32 from fold) -> Wc_bf[128][128].
// grid = 512 rows x 128 threads.
// ---------------------------------------------------------------------------
__global__ __launch_bounds__(128) void conv_kernel(
    const float* __restrict__ W_val, const float* __restrict__ b_val,
    const float* __restrict__ W_off, const float* __restrict__ b_off,
    const float* __restrict__ W_attn, const float* __restrict__ b_attn,
    const float* __restrict__ Wc, __hip_bfloat16* __restrict__ Wcat,
    float* __restrict__ bcat, __hip_bfloat16* __restrict__ Wc_bf) {
  int r = blockIdx.x, c = threadIdx.x;
  if (r < OPAD) {
    float v = 0.f, bv = 0.f;
    if (r < 128) { v = W_val[r * 128 + c]; bv = b_val[r]; }
    else if (r < 288) { v = W_off[(r - 128) * 128 + c]; bv = b_off[r - 128]; }
    else if (r < OCAT) { v = W_attn[(r - 288) * 128 + c]; bv = b_attn[r - 288]; }
    Wcat[(size_t)r * 128 + c] = __float2bfloat16(v);
    if (c == 0) bcat[r] = bv;
  } else {
    int rr = r - OPAD;  // 0..127
    Wc_bf[(size_t)rr * 128 + c] = __float2bfloat16(Wc[rr * 128 + c]);
  }
}

// ---------------------------------------------------------------------------
// MFMA bf16 GEMM: out[r][o] = dot(A[r], W[o]) + bias[o]
// A = src (+src2) fp32 -> bf16 staged in LDS; W = bf16 [OP][128].
// Block: 64 rows x 64 outs, 256 thr = 4 waves (2x2), each wave 32x32 via
// 2x2 fragments x 4 K-steps of mfma_f32_16x16x32_bf16.
// LDS granule swizzle g^(row&7) on 16B granules -> conflict-free-ish reads.
// MODE 0: scatter to head-major value/off/attn. MODE 1: row-major + resid.
// ---------------------------------------------------------------------------
template <int MODE, bool HAS_SRC2>
__global__ __launch_bounds__(256) void mfma_proj_kernel(
    const float* __restrict__ src, const float* __restrict__ src2,
    const __hip_bfloat16* __restrict__ Wb, const float* __restrict__ bias,
    float* __restrict__ value, float* __restrict__ offo,
    float* __restrict__ attno, float* __restrict__ out,
    const float* __restrict__ resid, int M, int Ototal) {
  __shared__ __hip_bfloat16 qa[64][128];
  __shared__ __hip_bfloat16 wb[64][128];
  const int t = threadIdx.x;
  const int r0 = blockIdx.x * 64;
  const int ot = blockIdx.y * 64;

  // stage A: fp32 (+src2) -> bf16, swizzled granules
#pragma unroll
  for (int i = 0; i < 4; ++i) {
    int lin = t + 256 * i;       // 0..1023
    int r = lin >> 4;            // row 0..63
    int g = lin & 15;            // granule 0..15 (8 bf16 each)
    int c = g << 3;
    float4 v0 = make_float4(0.f, 0.f, 0.f, 0.f);
    float4 v1 = make_float4(0.f, 0.f, 0.f, 0.f);
    if (r0 + r < M) {
      const float* p = src + (size_t)(r0 + r) * CDIM + c;
      v0 = *(const float4*)p;
      v1 = *(const float4*)(p + 4);
      if (HAS_SRC2) {
        const float* p2 = src2 + (size_t)(r0 + r) * CDIM + c;
        float4 u0 = *(const float4*)p2;
        float4 u1 = *(const float4*)(p2 + 4);
        v0.x += u0.x; v0.y += u0.y; v0.z += u0.z; v0.w += u0.w;
        v1.x += u1.x; v1.y += u1.y; v1.z += u1.z; v1.w += u1.w;
      }
    }
    __hip_bfloat16* dst = &qa[r][(g ^ (r & 7)) << 3];
    dst[0] = __float2bfloat16(v0.x); dst[1] = __float2bfloat16(v0.y);
    dst[2] = __float2bfloat16(v0.z); dst[3] = __float2bfloat16(v0.w);
    dst[4] = __float2bfloat16(v1.x); dst[5] = __float2bfloat16(v1.y);
    dst[6] = __float2bfloat16(v1.z); dst[7] = __float2bfloat16(v1.w);
  }
  // stage B: bf16 weights (OPAD-padded so always in-bounds), swizzled
#pragma unroll
  for (int i = 0; i < 4; ++i) {
    int lin = t + 256 * i;
    int r = lin >> 4;
    int g = lin & 15;
    short8v w = *(const short8v*)(Wb + (size_t)(ot + r) * 128 + (g << 3));
    *(short8v*)&wb[r][(g ^ (r & 7)) << 3] = w;
  }
  __syncthreads();

  const int wid = t >> 6;
  const int lane = t & 63;
  const int wr = (wid >> 1) * 32;  // wave row origin in tile
  const int wc = (wid & 1) * 32;   // wave col origin in tile
  const int lrow = lane & 15;
  const int lk = lane >> 4;        // 0..3

  f32x4 acc[2][2];
#pragma unroll
  for (int mi = 0; mi < 2; ++mi)
#pragma unroll
    for (int ni = 0; ni < 2; ++ni) acc[mi][ni] = (f32x4)(0.f);

#pragma unroll
  for (int kk = 0; kk < 4; ++kk) {
    const int gbase = kk * 4 + lk;  // granule 0..15
    int ra0 = wr + lrow, ra1 = wr + 16 + lrow;
    int rb0 = wc + lrow, rb1 = wc + 16 + lrow;
    short8v a0 = *(const short8v*)&qa[ra0][(gbase ^ (ra0 & 7)) << 3];
    short8v a1 = *(const short8v*)&qa[ra1][(gbase ^ (ra1 & 7)) << 3];
    short8v b0 = *(const short8v*)&wb[rb0][(gbase ^ (rb0 & 7)) << 3];
    short8v b1 = *(const short8v*)&wb[rb1][(gbase ^ (rb1 & 7)) << 3];
    acc[0][0] = __builtin_amdgcn_mfma_f32_16x16x32_bf16(a0, b0, acc[0][0], 0, 0, 0);
    acc[0][1] = __builtin_amdgcn_mfma_f32_16x16x32_bf16(a0, b1, acc[0][1], 0, 0, 0);
    acc[1][0] = __builtin_amdgcn_mfma_f32_16x16x32_bf16(a1, b0, acc[1][0], 0, 0, 0);
    acc[1][1] = __builtin_amdgcn_mfma_f32_16x16x32_bf16(a1, b1, acc[1][1], 0, 0, 0);
  }

  // epilogue: C/D layout col=lane&15, row=(lane>>4)*4+reg (m89)
  const int crow = (lane >> 4) * 2;  // *4 /2 ... (see below) -- actually *4
#pragma unroll
  for (int mi = 0; mi < 2; ++mi) {
#pragma unroll
    for (int ni = 0; ni < 2; ++ni) {
#pragma unroll
      for (int reg = 0; reg < 4; ++reg) {
        int r = r0 + wr + mi * 16 + (lane >> 4) * 4 + reg;
        int o = ot + wc + ni * 16 + (lane & 15);
        if (r >= M || o >= Ototal) continue;
        float v = acc[mi][ni][reg] + bias[o];
        if (MODE == 1) {
          out[(size_t)r * CDIM + o] = v + resid[(size_t)r * CDIM + o];
        } else {
          int b = r >= NTOK ? 1 : 0;
          int n = r - b * NTOK;
          if (o < 128) {
            int h = o >> 5, rem = o & 31;
            value[(((size_t)b * NHEAD + h) * NTOK + n) * 32 + rem] = v;
          } else if (o < 288) {
            int oo = o - 128, h = oo / 40, rem = oo - h * 40;
            offo[(((size_t)b * NHEAD + h) * NTOK + n) * 40 + rem] = v;
          } else {
            int oo = o - 288, h = oo / 20, rem = oo - h * 20;
            attno[(((size_t)b * NHEAD + h) * NTOK + n) * 20 + rem] = v;
          }
        }
      }
    }
  }
  (void)crow;
}

// ---------------------------------------------------------------------------
// Bilinear sampling + fused softmax. One (b,h) slice per block, slices pinned
// round-robin to XCDs via blockIdx.x & 7 (value slice = 1.28 MB < 4 MB L2).
// ---------------------------------------------------------------------------
__global__ __launch_bounds__(256) void sample_kernel(
    const float* __restrict__ value, const float* __restrict__ off,
    const float* __restrict__ attn, float* __restrict__ out) {
  const int s = blockIdx.x & 7;  // slice = b*NH + h
  const int blk = blockIdx.x >> 3;
  const int idx = blk * 256 + threadIdx.x;
  const int n = idx >> 3;
  if (n >= NTOK) return;
  const int d4 = idx & 7;
  const int b = s >> 2, h = s & 3;

  const float* vbase = value + (size_t)s * NTOK * DHEAD + d4 * 4;
  const float* obase = off + ((size_t)s * NTOK + n) * (NPNT * 2);
  const float* abase = attn + ((size_t)s * NTOK + n) * NPNT;

  float v[NPNT];
  float m = -1e30f;
#pragma unroll
  for (int i = 0; i < NPNT; ++i) {
    v[i] = abase[i];
    m = fmaxf(m, v[i]);
  }
  float ssum = 0.f;
#pragma unroll
  for (int i = 0; i < NPNT; ++i) {
    v[i] = __expf(v[i] - m);
    ssum += v[i];
  }
  const float inv = 1.f / ssum;

  const float fi = (float)(n / HWDIM);
  const float fj = (float)(n % HWDIM);
  float ax = 0.f, ay = 0.f, az = 0.f, aw4 = 0.f;
  for (int p = 0; p < NPNT; ++p) {
    float x = fi + obase[2 * p];
    float y = fj + obase[2 * p + 1];
    float aw = v[p] * inv;
    float x0f = floorf(x), y0f = floorf(y);
    int ix0 = (int)x0f, iy0 = (int)y0f;
    float wx1 = x - x0f, wy1 = y - y0f;
    float wx0 = 1.f - wx1, wy0 = 1.f - wy1;
#pragma unroll
    for (int cy = 0; cy < 2; ++cy) {
      int iy = iy0 + cy;
      if (iy < 0 || iy >= HWDIM) continue;
      float wy = cy ? wy1 : wy0;
#pragma unroll
      for (int cx = 0; cx < 2; ++cx) {
        int ix = ix0 + cx;
        if (ix < 0 || ix >= HWDIM) continue;
        float w = aw * wy * (cx ? wx1 : wx0);
        const float4 g =
            *(const float4*)(vbase + (size_t)(iy * HWDIM + ix) * DHEAD);
        ax += w * g.x; ay += w * g.y; az += w * g.z; aw4 += w * g.w;
      }
    }
  }
  *(float4*)(out + ((size_t)b * NTOK + n) * CDIM + h * DHEAD + d4 * 4) =
      make_float4(ax, ay, az, aw4);
}

extern "C" void kernel_launch(void* const* d_in, const int* in_sizes, int n_in,
                              void* d_out, int out_size, void* d_ws,
                              size_t ws_size, hipStream_t stream) {
  const float* query = (const float*)d_in[0];
  const float* query_pos = (const float*)d_in[1];
  const float* W_val = (const float*)d_in[2];
  const float* b_val = (const float*)d_in[3];
  const float* W_off = (const float*)d_in[4];
  const float* b_off = (const float*)d_in[5];
  const float* W_attn = (const float*)d_in[6];
  const float* b_attn = (const float*)d_in[7];
  const float* W_out1 = (const float*)d_in[8];
  const float* b_out1 = (const float*)d_in[9];
  const float* W_out2 = (const float*)d_in[10];
  const float* b_out2 = (const float*)d_in[11];
  float* out = (float*)d_out;

  float* value = (float*)d_ws;                  // (B*NH, N, 32)
  float* offb = value + (size_t)MROWS * CDIM;   // (B*NH, N, 40)
  float* attnb = offb + (size_t)MROWS * 160;    // (B*NH, N, 20) logits
  float* outat = attnb + (size_t)MROWS * 80;    // (B, N, C)
  float* Wc = outat + (size_t)MROWS * CDIM;     // (128,128) fp32
  float* bc = Wc + 128 * 128;                   // (128)
  float* bcat = bc + 128;                       // (384)
  __hip_bfloat16* Wcat = (__hip_bfloat16*)(bcat + OPAD);  // [384][128]
  __hip_bfloat16* Wc_bf = Wcat + (size_t)OPAD * 128;      // [128][128]

  fold_kernel<<<128, 128, 0, stream>>>(W_out1, b_out1, W_out2, b_out2, Wc, bc);
  conv_kernel<<<OPAD + 128, 128, 0, stream>>>(W_val, b_val, W_off, b_off,
                                              W_attn, b_attn, Wc, Wcat, bcat,
                                              Wc_bf);

  dim3 g1(313, OPAD / 64);  // 313 x 6
  mfma_proj_kernel<0, true><<<g1, 256, 0, stream>>>(
      query, query_pos, Wcat, bcat, value, offb, attnb, nullptr, nullptr,
      MROWS, OCAT);

  sample_kernel<<<313 * 8, 256, 0, stream>>>(value, offb, attnb, outat);

  dim3 g2(313, 2);
  mfma_proj_kernel<1, false><<<g2, 256, 0, stream>>>(
      outat, nullptr, Wc_bf, bc, nullptr, nullptr, nullptr, out, query, MROWS,
      128);
}

// Round 4
// 77.452 us; speedup vs baseline: 3.4446x; 1.2397x over previous
//
#include <hip/hip_runtime.h>
#include <hip/hip_bf16.h>
#include <math.h>

#define NTOK 10000
#define BATCH 2
#define CDIM 128
#define NHEAD 4
#define NPNT 20
#define DHEAD 32
#define HWDIM 100
#define MROWS (BATCH * NTOK)
#define OCAT 368   // 128 value + 160 off + 80 attn
#define OPAD 384   // padded to 64-multiple
#define PTOK 8     // 8x8 tokens per patch
#define PHALO 4    // halo cells each side (off std ~0.8 -> |off|<4 covers ~6-sigma)
#define PDIM 16    // PTOK + 2*PHALO
#define NPATCH 13  // ceil(100/8)
#define CELLPAD 40 // bf16 per cell in LDS (32 + 8 pad to spread banks)

typedef __attribute__((ext_vector_type(8))) short short8v;
typedef __attribute__((ext_vector_type(4))) short short4v;
typedef __attribute__((ext_vector_type(4))) float f32x4;

__device__ __forceinline__ float bf2f(short s) {
  union { unsigned u; float f; } c;
  c.u = ((unsigned)(unsigned short)s) << 16;
  return c.f;
}

// ---------------------------------------------------------------------------
// Fold the two output projections: Wc = W2 @ W1, bc = b2 + W2 @ b1 (fp32)
// ---------------------------------------------------------------------------
__global__ __launch_bounds__(128) void fold_kernel(
    const float* __restrict__ W1, const float* __restrict__ b1,
    const float* __restrict__ W2, const float* __restrict__ b2,
    float* __restrict__ Wc, float* __restrict__ bc) {
  __shared__ float w2row[128];
  __shared__ float red[128];
  int o = blockIdx.x, c = threadIdx.x;
  w2row[c] = W2[o * 128 + c];
  __syncthreads();
  float acc = 0.f;
  for (int k = 0; k < 128; ++k) acc += w2row[k] * W1[k * 128 + c];
  Wc[o * 128 + c] = acc;
  red[c] = w2row[c] * b1[c];
  __syncthreads();
  for (int s = 64; s > 0; s >>= 1) {
    if (c < s) red[c] += red[c + s];
    __syncthreads();
  }
  if (c == 0) bc[o] = b2[o] + red[0];
}

// ---------------------------------------------------------------------------
// Convert weights to bf16: Wcat[384][128] = {W_val,W_off,W_attn,pad},
// bcat[384] = {b_val,b_off,b_attn,0}; Wc(fp32 from fold) -> Wc_bf[128][128].
// ---------------------------------------------------------------------------
__global__ __launch_bounds__(128) void conv_kernel(
    const float* __restrict__ W_val, const float* __restrict__ b_val,
    const float* __restrict__ W_off, const float* __restrict__ b_off,
    const float* __restrict__ W_attn, const float* __restrict__ b_attn,
    const float* __restrict__ Wc, __hip_bfloat16* __restrict__ Wcat,
    float* __restrict__ bcat, __hip_bfloat16* __restrict__ Wc_bf) {
  int r = blockIdx.x, c = threadIdx.x;
  if (r < OPAD) {
    float v = 0.f, bv = 0.f;
    if (r < 128) { v = W_val[r * 128 + c]; bv = b_val[r]; }
    else if (r < 288) { v = W_off[(r - 128) * 128 + c]; bv = b_off[r - 128]; }
    else if (r < OCAT) { v = W_attn[(r - 288) * 128 + c]; bv = b_attn[r - 288]; }
    Wcat[(size_t)r * 128 + c] = __float2bfloat16(v);
    if (c == 0) bcat[r] = bv;
  } else {
    int rr = r - OPAD;
    Wc_bf[(size_t)rr * 128 + c] = __float2bfloat16(Wc[rr * 128 + c]);
  }
}

// ---------------------------------------------------------------------------
// MFMA bf16 GEMM.  AKIND 0: A = fp32 src+src2 -> bf16.  AKIND 1: A = bf16 src.
// MODE 0: scatter to head-major value(bf16)/off/attn.  MODE 1: row-major
// fp32 + residual.
// 64 rows x 64 outs, 4 waves (2x2), each 32x32 via 2x2 frags x 4 K-steps.
// ---------------------------------------------------------------------------
template <int MODE, int AKIND>
__global__ __launch_bounds__(256) void mfma_proj_kernel(
    const float* __restrict__ src_f, const float* __restrict__ src2,
    const __hip_bfloat16* __restrict__ src_b,
    const __hip_bfloat16* __restrict__ Wb, const float* __restrict__ bias,
    __hip_bfloat16* __restrict__ value, float* __restrict__ offo,
    float* __restrict__ attno, float* __restrict__ out,
    const float* __restrict__ resid, int M, int Ototal) {
  __shared__ __hip_bfloat16 qa[64][128];
  __shared__ __hip_bfloat16 wb[64][128];
  const int t = threadIdx.x;
  const int r0 = blockIdx.x * 64;
  const int ot = blockIdx.y * 64;

#pragma unroll
  for (int i = 0; i < 4; ++i) {
    int lin = t + 256 * i;  // 0..1023
    int r = lin >> 4;       // row 0..63
    int g = lin & 15;       // 16B granule
    if (AKIND == 0) {
      int c = g << 3;
      float4 v0 = make_float4(0.f, 0.f, 0.f, 0.f);
      float4 v1 = make_float4(0.f, 0.f, 0.f, 0.f);
      if (r0 + r < M) {
        const float* p = src_f + (size_t)(r0 + r) * CDIM + c;
        v0 = *(const float4*)p;
        v1 = *(const float4*)(p + 4);
        const float* p2 = src2 + (size_t)(r0 + r) * CDIM + c;
        float4 u0 = *(const float4*)p2;
        float4 u1 = *(const float4*)(p2 + 4);
        v0.x += u0.x; v0.y += u0.y; v0.z += u0.z; v0.w += u0.w;
        v1.x += u1.x; v1.y += u1.y; v1.z += u1.z; v1.w += u1.w;
      }
      __hip_bfloat16* dst = &qa[r][(g ^ (r & 7)) << 3];
      dst[0] = __float2bfloat16(v0.x); dst[1] = __float2bfloat16(v0.y);
      dst[2] = __float2bfloat16(v0.z); dst[3] = __float2bfloat16(v0.w);
      dst[4] = __float2bfloat16(v1.x); dst[5] = __float2bfloat16(v1.y);
      dst[6] = __float2bfloat16(v1.z); dst[7] = __float2bfloat16(v1.w);
    } else {
      short8v v = (short8v)(short)0;
      if (r0 + r < M)
        v = *(const short8v*)(src_b + (size_t)(r0 + r) * CDIM + (g << 3));
      *(short8v*)&qa[r][(g ^ (r & 7)) << 3] = v;
    }
  }
#pragma unroll
  for (int i = 0; i < 4; ++i) {
    int lin = t + 256 * i;
    int r = lin >> 4;
    int g = lin & 15;
    short8v w = *(const short8v*)(Wb + (size_t)(ot + r) * 128 + (g << 3));
    *(short8v*)&wb[r][(g ^ (r & 7)) << 3] = w;
  }
  __syncthreads();

  const int wid = t >> 6;
  const int lane = t & 63;
  const int wr = (wid >> 1) * 32;
  const int wc = (wid & 1) * 32;
  const int lrow = lane & 15;
  const int lk = lane >> 4;

  f32x4 acc[2][2];
#pragma unroll
  for (int mi = 0; mi < 2; ++mi)
#pragma unroll
    for (int ni = 0; ni < 2; ++ni) acc[mi][ni] = (f32x4)(0.f);

#pragma unroll
  for (int kk = 0; kk < 4; ++kk) {
    const int gbase = kk * 4 + lk;
    int ra0 = wr + lrow, ra1 = wr + 16 + lrow;
    int rb0 = wc + lrow, rb1 = wc + 16 + lrow;
    short8v a0 = *(const short8v*)&qa[ra0][(gbase ^ (ra0 & 7)) << 3];
    short8v a1 = *(const short8v*)&qa[ra1][(gbase ^ (ra1 & 7)) << 3];
    short8v b0 = *(const short8v*)&wb[rb0][(gbase ^ (rb0 & 7)) << 3];
    short8v b1 = *(const short8v*)&wb[rb1][(gbase ^ (rb1 & 7)) << 3];
    acc[0][0] = __builtin_amdgcn_mfma_f32_16x16x32_bf16(a0, b0, acc[0][0], 0, 0, 0);
    acc[0][1] = __builtin_amdgcn_mfma_f32_16x16x32_bf16(a0, b1, acc[0][1], 0, 0, 0);
    acc[1][0] = __builtin_amdgcn_mfma_f32_16x16x32_bf16(a1, b0, acc[1][0], 0, 0, 0);
    acc[1][1] = __builtin_amdgcn_mfma_f32_16x16x32_bf16(a1, b1, acc[1][1], 0, 0, 0);
  }

  // C/D layout: col = lane&15, row = (lane>>4)*4 + reg  (m89)
#pragma unroll
  for (int mi = 0; mi < 2; ++mi) {
#pragma unroll
    for (int ni = 0; ni < 2; ++ni) {
#pragma unroll
      for (int reg = 0; reg < 4; ++reg) {
        int r = r0 + wr + mi * 16 + (lane >> 4) * 4 + reg;
        int o = ot + wc + ni * 16 + (lane & 15);
        if (r >= M || o >= Ototal) continue;
        float v = acc[mi][ni][reg] + bias[o];
        if (MODE == 1) {
          out[(size_t)r * CDIM + o] = v + resid[(size_t)r * CDIM + o];
        } else {
          int b = r >= NTOK ? 1 : 0;
          int n = r - b * NTOK;
          if (o < 128) {
            int h = o >> 5, rem = o & 31;
            value[(((size_t)b * NHEAD + h) * NTOK + n) * 32 + rem] =
                __float2bfloat16(v);
          } else if (o < 288) {
            int oo = o - 128, h = oo / 40, rem = oo - h * 40;
            offo[(((size_t)b * NHEAD + h) * NTOK + n) * 40 + rem] = v;
          } else {
            int oo = o - 288, h = oo / 20, rem = oo - h * 20;
            attno[(((size_t)b * NHEAD + h) * NTOK + n) * 20 + rem] = v;
          }
        }
      }
    }
  }
}

// ---------------------------------------------------------------------------
// Sampling with LDS patch staging. Block = one (b,h) slice x one 8x8 token
// patch. Stage 16x16 halo'd bf16 value cells (zeros outside image -> free
// boundary handling). Token (i,j) samples near cell (j,i) (transposed per the
// reference's coord convention). Rare out-of-patch samples take a global
// fallback. 8 lanes per token (4 dims each). Output stored bf16 (b,n,c).
// ---------------------------------------------------------------------------
__global__ __launch_bounds__(256) void sample_kernel(
    const __hip_bfloat16* __restrict__ value, const float* __restrict__ off,
    const float* __restrict__ attn, __hip_bfloat16* __restrict__ outat) {
  const int s = blockIdx.x & 7;        // slice = b*NH+h; low bits -> XCD spread
  const int pidx = blockIdx.x >> 3;
  const int PI = pidx % NPATCH, PJ = pidx / NPATCH;
  const int I0 = PI * PTOK, J0 = PJ * PTOK;
  const int b = s >> 2, h = s & 3;

  __shared__ __hip_bfloat16 patch[PDIM * PDIM][CELLPAD];
  const __hip_bfloat16* vglob = value + (size_t)s * NTOK * DHEAD;

  // stage 256 cells x 64B, coalesced 16B chunks; zeros outside image
#pragma unroll
  for (int it = 0; it < 4; ++it) {
    int lin = threadIdx.x + 256 * it;  // 0..1023
    int cell = lin >> 2, part = lin & 3;
    int py = cell >> 4, px = cell & 15;
    int gy = J0 - PHALO + py;  // j-dimension (multiplies HWDIM)
    int gx = I0 - PHALO + px;  // i-dimension
    short8v v = (short8v)(short)0;
    if (gy >= 0 && gy < HWDIM && gx >= 0 && gx < HWDIM)
      v = *(const short8v*)(vglob + ((size_t)(gy * HWDIM + gx)) * DHEAD +
                            part * 8);
    *(short8v*)&patch[cell][part * 8] = v;
  }
  __syncthreads();

  const int d4 = threadIdx.x & 7;
  const int slot = threadIdx.x >> 3;  // 0..31

  for (int tt = 0; tt < 2; ++tt) {
    int tl = slot + 32 * tt;      // 0..63
    int li = tl & 7, lj = tl >> 3;
    int i = I0 + li, j = J0 + lj;
    if (i >= HWDIM || j >= HWDIM) continue;
    int n = i * HWDIM + j;

    const float* obase = off + ((size_t)s * NTOK + n) * (NPNT * 2);
    const float* abase = attn + ((size_t)s * NTOK + n) * NPNT;

    float v[NPNT];
    float m = -1e30f;
#pragma unroll
    for (int p = 0; p < NPNT; ++p) {
      v[p] = abase[p];
      m = fmaxf(m, v[p]);
    }
    float ssum = 0.f;
#pragma unroll
    for (int p = 0; p < NPNT; ++p) {
      v[p] = __expf(v[p] - m);
      ssum += v[p];
    }
    const float inv = 1.f / ssum;

    const float fi = (float)i, fj = (float)j;
    float ax = 0.f, ay = 0.f, az = 0.f, aw4 = 0.f;
#pragma unroll
    for (int p = 0; p < NPNT; ++p) {
      float x = fi + obase[2 * p];      // i-dim coordinate
      float y = fj + obase[2 * p + 1];  // j-dim coordinate (multiplies HWDIM)
      float aw = v[p] * inv;
      float x0f = floorf(x), y0f = floorf(y);
      int ix0 = (int)x0f, iy0 = (int)y0f;
      float wx1 = x - x0f, wy1 = y - y0f;
      float wx0 = 1.f - wx1, wy0 = 1.f - wy1;
      float w00 = aw * wy0 * wx0, w01 = aw * wy0 * wx1;
      float w10 = aw * wy1 * wx0, w11 = aw * wy1 * wx1;
      int ly = iy0 - (J0 - PHALO);
      int lx = ix0 - (I0 - PHALO);
      if (ly >= 0 && ly <= PDIM - 2 && lx >= 0 && lx <= PDIM - 2) {
        const __hip_bfloat16* pb = &patch[ly * PDIM + lx][d4 * 4];
        short4v g00 = *(const short4v*)pb;
        short4v g01 = *(const short4v*)(pb + CELLPAD);
        short4v g10 = *(const short4v*)(pb + PDIM * CELLPAD);
        short4v g11 = *(const short4v*)(pb + PDIM * CELLPAD + CELLPAD);
        ax += w00 * bf2f(g00.x) + w01 * bf2f(g01.x) + w10 * bf2f(g10.x) + w11 * bf2f(g11.x);
        ay += w00 * bf2f(g00.y) + w01 * bf2f(g01.y) + w10 * bf2f(g10.y) + w11 * bf2f(g11.y);
        az += w00 * bf2f(g00.z) + w01 * bf2f(g01.z) + w10 * bf2f(g10.z) + w11 * bf2f(g11.z);
        aw4 += w00 * bf2f(g00.w) + w01 * bf2f(g01.w) + w10 * bf2f(g10.w) + w11 * bf2f(g11.w);
      } else {
        // rare out-of-patch fallback: direct (L2) gather with bounds checks
        float wgt[4] = {w00, w01, w10, w11};
#pragma unroll
        for (int cy = 0; cy < 2; ++cy) {
          int iy = iy0 + cy;
          if (iy < 0 || iy >= HWDIM) continue;
#pragma unroll
          for (int cx = 0; cx < 2; ++cx) {
            int ix = ix0 + cx;
            if (ix < 0 || ix >= HWDIM) continue;
            float w = wgt[cy * 2 + cx];
            short4v g = *(const short4v*)(vglob +
                                          ((size_t)(iy * HWDIM + ix)) * DHEAD +
                                          d4 * 4);
            ax += w * bf2f(g.x); ay += w * bf2f(g.y);
            az += w * bf2f(g.z); aw4 += w * bf2f(g.w);
          }
        }
      }
    }
    union { short4v v4; __hip_bfloat16 hh[4]; } o;
    o.hh[0] = __float2bfloat16(ax); o.hh[1] = __float2bfloat16(ay);
    o.hh[2] = __float2bfloat16(az); o.hh[3] = __float2bfloat16(aw4);
    *(short4v*)(outat + ((size_t)b * NTOK + n) * CDIM + h * DHEAD + d4 * 4) =
        o.v4;
  }
}

extern "C" void kernel_launch(void* const* d_in, const int* in_sizes, int n_in,
                              void* d_out, int out_size, void* d_ws,
                              size_t ws_size, hipStream_t stream) {
  const float* query = (const float*)d_in[0];
  const float* query_pos = (const float*)d_in[1];
  const float* W_val = (const float*)d_in[2];
  const float* b_val = (const float*)d_in[3];
  const float* W_off = (const float*)d_in[4];
  const float* b_off = (const float*)d_in[5];
  const float* W_attn = (const float*)d_in[6];
  const float* b_attn = (const float*)d_in[7];
  const float* W_out1 = (const float*)d_in[8];
  const float* b_out1 = (const float*)d_in[9];
  const float* W_out2 = (const float*)d_in[10];
  const float* b_out2 = (const float*)d_in[11];
  float* out = (float*)d_out;

  char* ws = (char*)d_ws;
  __hip_bfloat16* value = (__hip_bfloat16*)ws;            // (B*NH,N,32) bf16
  ws += (size_t)MROWS * CDIM * 2;
  float* offb = (float*)ws;                               // (B*NH,N,40) f32
  ws += (size_t)MROWS * 160 * 4;
  float* attnb = (float*)ws;                              // (B*NH,N,20) f32
  ws += (size_t)MROWS * 80 * 4;
  __hip_bfloat16* outat = (__hip_bfloat16*)ws;            // (B,N,C) bf16
  ws += (size_t)MROWS * CDIM * 2;
  float* Wc = (float*)ws; ws += 128 * 128 * 4;
  float* bc = (float*)ws; ws += 128 * 4;
  float* bcat = (float*)ws; ws += OPAD * 4;
  __hip_bfloat16* Wcat = (__hip_bfloat16*)ws; ws += (size_t)OPAD * 128 * 2;
  __hip_bfloat16* Wc_bf = (__hip_bfloat16*)ws;

  fold_kernel<<<128, 128, 0, stream>>>(W_out1, b_out1, W_out2, b_out2, Wc, bc);
  conv_kernel<<<OPAD + 128, 128, 0, stream>>>(W_val, b_val, W_off, b_off,
                                              W_attn, b_attn, Wc, Wcat, bcat,
                                              Wc_bf);

  dim3 g1(313, OPAD / 64);  // 313 x 6
  mfma_proj_kernel<0, 0><<<g1, 256, 0, stream>>>(
      query, query_pos, nullptr, Wcat, bcat, value, offb, attnb, nullptr,
      nullptr, MROWS, OCAT);

  sample_kernel<<<8 * NPATCH * NPATCH, 256, 0, stream>>>(value, offb, attnb,
                                                         outat);

  dim3 g2(313, 2);
  mfma_proj_kernel<1, 1><<<g2, 256, 0, stream>>>(
      nullptr, nullptr, outat, Wc_bf, bc, nullptr, nullptr, nullptr, out,
      query, MROWS, 128);
}